// Round 1
// baseline (425.332 us; speedup 1.0000x reference)
//
#include <hip/hip_runtime.h>
#include <math.h>

// ArcFace loss, fully fused:
//   K1: row-normalize feature (f32) -> bf16 feat_n            (512x512)
//   K2: bf16-MFMA GEMM over header, ONE pass, epilogue accumulates
//       per-row moments {S|x|, Sx, Sx^2, Sx^3, Sx^4} + t_orig (no logits to HBM)
//   K3: per-row f64 series LSE + arccos-margin + mean
//
// LSE via Taylor moments is valid because |s*x/sum_abs| <= ~0.005 for this
// data scale (series truncation error ~1e-16 rel). Margin term handled exactly.

#define B_ROWS 512
#define K_DIM  512
#define C_COLS 85742
#define BN 64
#define BK 32
#define LDB 40              // padded LDS stride (bf16 elems): 32 + 8
#define NKS (K_DIM / BK)    // 16

typedef float  f32x4  __attribute__((ext_vector_type(4)));
typedef short  bf16x8 __attribute__((ext_vector_type(8)));
typedef unsigned short u16x8 __attribute__((ext_vector_type(8)));

__device__ __forceinline__ unsigned short f2bf(float f) {
  // round-to-nearest-even f32 -> bf16 (inputs are finite normals)
  unsigned int u = __float_as_uint(f);
  u += 0x7fffu + ((u >> 16) & 1u);
  return (unsigned short)(u >> 16);
}

// ---------------- K1: L2-normalize rows of feature, emit bf16 ----------------
__global__ __launch_bounds__(64)
void normalize_kernel(const float* __restrict__ feature,
                      unsigned short* __restrict__ feat_bf) {
  const int row  = blockIdx.x;
  const int lane = threadIdx.x;
  const float* src = feature + (size_t)row * K_DIM + lane * 8;
  f32x4 v0 = *(const f32x4*)src;
  f32x4 v1 = *(const f32x4*)(src + 4);
  float ss = v0[0]*v0[0] + v0[1]*v0[1] + v0[2]*v0[2] + v0[3]*v0[3]
           + v1[0]*v1[0] + v1[1]*v1[1] + v1[2]*v1[2] + v1[3]*v1[3];
  #pragma unroll
  for (int m = 1; m < 64; m <<= 1) ss += __shfl_xor(ss, m);
  const float scale = 1.0f / fmaxf(sqrtf(ss), 1e-12f);
  u16x8 o;
  o[0] = f2bf(v0[0] * scale); o[1] = f2bf(v0[1] * scale);
  o[2] = f2bf(v0[2] * scale); o[3] = f2bf(v0[3] * scale);
  o[4] = f2bf(v1[0] * scale); o[5] = f2bf(v1[1] * scale);
  o[6] = f2bf(v1[2] * scale); o[7] = f2bf(v1[3] * scale);
  *(u16x8*)(feat_bf + (size_t)row * K_DIM + lane * 8) = o;
}

// ------- K2: fused GEMM (BM=512 all rows, BN=64 cols/block) + moments --------
// header read exactly once (f32 -> bf16 in-register during staging).
// A-fragments (feat_n bf16, 512 KB) read straight from global (L2-resident).
__global__ __launch_bounds__(512, 2)
void gemm_moments_kernel(const float* __restrict__ header,
                         const unsigned short* __restrict__ feat_bf,
                         const long long* __restrict__ label,
                         float* __restrict__ moments,   // [5][512]
                         float* __restrict__ t_orig) {  // [512]
  __shared__ unsigned short b_lds[2][BN * LDB];
  __shared__ int lds_label[B_ROWS];

  const int tid = threadIdx.x;
  const int c0  = blockIdx.x * BN;

  lds_label[tid] = (int)label[tid];   // 512 threads == 512 rows

  const int wave = tid >> 6;
  const int lane = tid & 63;
  const int g    = lane >> 4;
  const int l16  = lane & 15;
  const int wrow = wave * 64;

  // staging decomposition: 256 threads, each a 2(k) x 4(c) micro-block
  const bool stager  = tid < 256;
  const int  kr      = ((tid >> 4) & 15) * 2;   // even k-row in [0,32)
  const int  c_local = (tid & 15) * 4;
  const int  cg      = c0 + c_local;

  f32x4 acc[4][4] = {};   // wave tile 64x64 -> 4x4 frags of 16x16
  f32x4 va, vb;

  // prologue: stage ks=0 into buf 0
  if (stager) {
    const float* p = header + (size_t)kr * C_COLS + cg;
    if (cg + 3 < C_COLS) { va = *(const f32x4*)p; vb = *(const f32x4*)(p + C_COLS); }
    else {
      #pragma unroll
      for (int j = 0; j < 4; ++j) {
        const bool ok = (cg + j) < C_COLS;
        va[j] = ok ? p[j] : 0.f;
        vb[j] = ok ? p[C_COLS + j] : 0.f;
      }
    }
    #pragma unroll
    for (int j = 0; j < 4; ++j) {
      const unsigned int pk = ((unsigned int)f2bf(vb[j]) << 16) | (unsigned int)f2bf(va[j]);
      *(unsigned int*)&b_lds[0][(c_local + j) * LDB + kr] = pk;   // [c][k], k-pair
    }
  }
  __syncthreads();

  for (int ks = 0; ks < NKS; ++ks) {
    const int  buf  = ks & 1;
    const bool more = (ks + 1) < NKS;

    // T14-style: issue next tile's global loads before compute
    if (stager && more) {
      const float* p = header + ((size_t)(ks + 1) * BK + kr) * C_COLS + cg;
      if (cg + 3 < C_COLS) { va = *(const f32x4*)p; vb = *(const f32x4*)(p + C_COLS); }
      else {
        #pragma unroll
        for (int j = 0; j < 4; ++j) {
          const bool ok = (cg + j) < C_COLS;
          va[j] = ok ? p[j] : 0.f;
          vb[j] = ok ? p[C_COLS + j] : 0.f;
        }
      }
    }

    bf16x8 afrag[4], bfrag[4];
    #pragma unroll
    for (int mi = 0; mi < 4; ++mi)  // A: row = lane&15, k = 8g+j (k-contig in feat)
      afrag[mi] = *(const bf16x8*)(feat_bf +
                   (size_t)(wrow + mi * 16 + l16) * K_DIM + ks * BK + g * 8);
    #pragma unroll
    for (int ni = 0; ni < 4; ++ni)  // B: col = lane&15, k = 8g+j ([c][k] LDS layout)
      bfrag[ni] = *(const bf16x8*)&b_lds[buf][(ni * 16 + l16) * LDB + g * 8];

    #pragma unroll
    for (int mi = 0; mi < 4; ++mi)
      #pragma unroll
      for (int ni = 0; ni < 4; ++ni)
        acc[mi][ni] = __builtin_amdgcn_mfma_f32_16x16x32_bf16(
                        afrag[mi], bfrag[ni], acc[mi][ni], 0, 0, 0);

    // write next tile after MFMAs (loads overlapped with compute)
    if (stager && more) {
      #pragma unroll
      for (int j = 0; j < 4; ++j) {
        const unsigned int pk = ((unsigned int)f2bf(vb[j]) << 16) | (unsigned int)f2bf(va[j]);
        *(unsigned int*)&b_lds[buf ^ 1][(c_local + j) * LDB + kr] = pk;
      }
    }
    __syncthreads();
  }

  // epilogue: per-row moment partials over this block's 64 cols.
  // C/D layout (verified m89): col = lane&15, row = (lane>>4)*4 + reg.
  // Padded cols produced x==0 -> contribute 0 to every moment (safe).
  #pragma unroll
  for (int mi = 0; mi < 4; ++mi) {
    #pragma unroll
    for (int r = 0; r < 4; ++r) {
      const int row = wrow + mi * 16 + g * 4 + r;
      const int lbl = lds_label[row];
      float sa = 0.f, s1 = 0.f, s2 = 0.f, s3 = 0.f, s4 = 0.f;
      #pragma unroll
      for (int ni = 0; ni < 4; ++ni) {
        const float x = acc[mi][ni][r];
        const int col = c0 + ni * 16 + l16;
        if (col == lbl) t_orig[row] = x;   // unique writer across the grid
        const float ax = fabsf(x), x2 = x * x;
        sa += ax; s1 += x; s2 += x2; s3 += x2 * x; s4 += x2 * x2;
      }
      #pragma unroll
      for (int m = 1; m < 16; m <<= 1) {   // reduce across the 16 col-lanes
        sa += __shfl_xor(sa, m);
        s1 += __shfl_xor(s1, m);
        s2 += __shfl_xor(s2, m);
        s3 += __shfl_xor(s3, m);
        s4 += __shfl_xor(s4, m);
      }
      if (l16 == 0) {
        atomicAdd(&moments[0 * B_ROWS + row], sa);
        atomicAdd(&moments[1 * B_ROWS + row], s1);
        atomicAdd(&moments[2 * B_ROWS + row], s2);
        atomicAdd(&moments[3 * B_ROWS + row], s3);
        atomicAdd(&moments[4 * B_ROWS + row], s4);
      }
    }
  }
}

// ---------------- K3: per-row series LSE + margin + mean (f64) ----------------
__global__ __launch_bounds__(512)
void loss_kernel(const float* __restrict__ moments,
                 const float* __restrict__ t_orig,
                 float* __restrict__ out) {
  const int r = threadIdx.x;
  const double A  = (double)moments[0 * B_ROWS + r];
  const double S1 = (double)moments[1 * B_ROWS + r];
  const double S2 = (double)moments[2 * B_ROWS + r];
  const double S3 = (double)moments[3 * B_ROWS + r];
  const double S4 = (double)moments[4 * B_ROWS + r];
  const double to = (double)t_orig[r];
  const double z  = 64.0 / A;   // S / sum|x|
  // sum_c exp(s*x_c/A) over ALL real columns via Taylor moments
  double sumexp = (double)C_COLS
                + z * (S1 + z * (0.5 * S2 + z * ((1.0/6.0) * S3 + z * (1.0/24.0) * S4)));
  double t = to / A;
  t = fmin(fmax(t, -1.0), 1.0);
  const double tm = cos(acos(t) + 0.5);          // margin M = 0.5
  sumexp += exp(64.0 * tm) - exp(z * to);        // swap target term exactly
  double v = log(sumexp) - 64.0 * tm;            // lse - s*t_m

  #pragma unroll
  for (int m = 1; m < 64; m <<= 1) v += __shfl_xor(v, m);
  __shared__ double red[8];
  if ((r & 63) == 0) red[r >> 6] = v;
  __syncthreads();
  if (r == 0) {
    double tot = 0.0;
    #pragma unroll
    for (int i = 0; i < 8; ++i) tot += red[i];
    out[0] = (float)(tot / (double)B_ROWS);
  }
}

extern "C" void kernel_launch(void* const* d_in, const int* in_sizes, int n_in,
                              void* d_out, int out_size, void* d_ws, size_t ws_size,
                              hipStream_t stream) {
  const float*     feature = (const float*)d_in[0];
  const float*     header  = (const float*)d_in[1];
  const long long* label   = (const long long*)d_in[2];
  float* out = (float*)d_out;

  // ws layout: moments[5][512] | t_orig[512] | feat_bf[512*512] (bf16)
  float* moments = (float*)d_ws;
  float* t_orig  = moments + 5 * B_ROWS;
  unsigned short* feat_bf = (unsigned short*)(moments + 6 * B_ROWS);

  hipMemsetAsync(d_ws, 0, 6 * B_ROWS * sizeof(float), stream);
  normalize_kernel<<<B_ROWS, 64, 0, stream>>>(feature, feat_bf);
  const int nblocks = (C_COLS + BN - 1) / BN;   // 1340
  gemm_moments_kernel<<<nblocks, 512, 0, stream>>>(header, feat_bf, label, moments, t_orig);
  loss_kernel<<<1, 512, 0, stream>>>(moments, t_orig, out);
}

// Round 5
// 361.794 us; speedup vs baseline: 1.1756x; 1.1756x over previous
//
#include <hip/hip_runtime.h>
#include <math.h>

// ArcFace loss, fully fused, one pass over header:
//   K1: row-normalize feature (f32) -> bf16 feat_n            (512x512)
//   K2: bf16-MFMA GEMM over header, epilogue accumulates per-row moments
//       {S|x|, Sx, Sx^2, Sx^3, Sx^4} + t_orig into 64 REPLICA buffers
//       (plain uncontended atomics; logits never touch HBM)
//   K3: reduce replicas + per-row f64 series LSE + margin + mean
//
// LSE via Taylor moments: |s*x/sum_abs| <= ~0.005 -> 4th-order series is
// ~1e-16 relative. Target-class term swapped exactly in f64.

#define B_ROWS 512
#define K_DIM  512
#define C_COLS 85742
#define BN 64
#define BK 32
#define LDB 40              // bf16 elems per col-row (80B stride, 16B-aligned)
#define NKS (K_DIM / BK)    // 16
#define NREP 64             // moment replica count

typedef float  f32x4  __attribute__((ext_vector_type(4)));
typedef short  bf16x8 __attribute__((ext_vector_type(8)));
typedef unsigned short u16x8 __attribute__((ext_vector_type(8)));
typedef unsigned int   u32x4 __attribute__((ext_vector_type(4)));

__device__ __forceinline__ unsigned short f2bf(float f) {
  unsigned int u = __float_as_uint(f);
  u += 0x7fffu + ((u >> 16) & 1u);
  return (unsigned short)(u >> 16);
}

// ---------------- K1: L2-normalize rows of feature, emit bf16 ----------------
__global__ __launch_bounds__(64)
void normalize_kernel(const float* __restrict__ feature,
                      unsigned short* __restrict__ feat_bf) {
  const int row  = blockIdx.x;
  const int lane = threadIdx.x;
  const float* src = feature + (size_t)row * K_DIM + lane * 8;
  f32x4 v0 = *(const f32x4*)src;
  f32x4 v1 = *(const f32x4*)(src + 4);
  float ss = v0[0]*v0[0] + v0[1]*v0[1] + v0[2]*v0[2] + v0[3]*v0[3]
           + v1[0]*v1[0] + v1[1]*v1[1] + v1[2]*v1[2] + v1[3]*v1[3];
  #pragma unroll
  for (int m = 1; m < 64; m <<= 1) ss += __shfl_xor(ss, m);
  const float scale = 1.0f / fmaxf(sqrtf(ss), 1e-12f);
  u16x8 o;
  o[0] = f2bf(v0[0] * scale); o[1] = f2bf(v0[1] * scale);
  o[2] = f2bf(v0[2] * scale); o[3] = f2bf(v0[3] * scale);
  o[4] = f2bf(v1[0] * scale); o[5] = f2bf(v1[1] * scale);
  o[6] = f2bf(v1[2] * scale); o[7] = f2bf(v1[3] * scale);
  *(u16x8*)(feat_bf + (size_t)row * K_DIM + lane * 8) = o;
}

// ------- K2: fused GEMM (BM=512 all rows, BN=64 cols/block) + moments --------
__global__ __launch_bounds__(512, 4)   // 4 waves/EU -> 2 blocks/CU
void gemm_moments_kernel(const float* __restrict__ header,
                         const unsigned short* __restrict__ feat_bf,
                         const long long* __restrict__ label,
                         float* __restrict__ moments_rep,  // [NREP][5][512]
                         float* __restrict__ t_orig) {     // [512]
  __shared__ unsigned short b_lds[2][BN * LDB];
  __shared__ int lds_label[B_ROWS];

  const int tid = threadIdx.x;
  const int c0  = blockIdx.x * BN;

  lds_label[tid] = (int)label[tid];   // 512 threads == 512 rows

  const int wave = tid >> 6;
  const int lane = tid & 63;
  const int g    = lane >> 4;
  const int l16  = lane & 15;
  const int wrow = wave * 64;

  // staging: 256 threads; thread = (col c_l in [0,64), k-octet w8 in {0,8,16,24})
  const bool stager = tid < 256;
  const int  c_l    = tid & 63;
  const int  w8     = (tid >> 6) * 8;
  const bool cok    = (c0 + c_l) < C_COLS;
  const int  cg     = cok ? (c0 + c_l) : 0;   // clamp OOB cols to 0, zero later

  f32x4 acc[4][4] = {};
  float v[8];

  // prologue: stage ks=0 into buf 0 (8 coalesced dword loads, one b128 write)
  if (stager) {
    const float* p = header + (size_t)w8 * C_COLS + cg;
    #pragma unroll
    for (int j = 0; j < 8; ++j) v[j] = p[(size_t)j * C_COLS];
    #pragma unroll
    for (int j = 0; j < 8; ++j) if (!cok) v[j] = 0.f;
    u32x4 d;
    #pragma unroll
    for (int i = 0; i < 4; ++i)
      d[i] = ((unsigned int)f2bf(v[2*i+1]) << 16) | (unsigned int)f2bf(v[2*i]);
    *(u32x4*)&b_lds[0][c_l * LDB + w8] = d;    // byte 80*c + 16*w: 16B-aligned
  }
  __syncthreads();

  for (int ks = 0; ks < NKS; ++ks) {
    const int  buf  = ks & 1;
    const bool more = (ks + 1) < NKS;

    // 1) afrag global loads FIRST (MFMA will wait only on these: vmcnt(2-ish))
    bf16x8 afrag[4];
    #pragma unroll
    for (int mi = 0; mi < 4; ++mi)
      afrag[mi] = *(const bf16x8*)(feat_bf +
                   (size_t)(wrow + mi * 16 + l16) * K_DIM + ks * BK + g * 8);

    // 2) header prefetch for ks+1 (issued AFTER afrag -> stays in flight)
    if (stager && more) {
      const float* p = header + ((size_t)(ks + 1) * BK + w8) * C_COLS + cg;
      #pragma unroll
      for (int j = 0; j < 8; ++j) v[j] = p[(size_t)j * C_COLS];
    }

    // 3) bfrag LDS reads (uniform 8 dwords/bank -> conflict-free b128)
    bf16x8 bfrag[4];
    #pragma unroll
    for (int ni = 0; ni < 4; ++ni)
      bfrag[ni] = *(const bf16x8*)&b_lds[buf][(ni * 16 + l16) * LDB + g * 8];

    // 4) MFMAs
    #pragma unroll
    for (int mi = 0; mi < 4; ++mi)
      #pragma unroll
      for (int ni = 0; ni < 4; ++ni)
        acc[mi][ni] = __builtin_amdgcn_mfma_f32_16x16x32_bf16(
                        afrag[mi], bfrag[ni], acc[mi][ni], 0, 0, 0);

    // 5) pack + conflict-free b128 write of next tile
    if (stager && more) {
      #pragma unroll
      for (int j = 0; j < 8; ++j) if (!cok) v[j] = 0.f;
      u32x4 d;
      #pragma unroll
      for (int i = 0; i < 4; ++i)
        d[i] = ((unsigned int)f2bf(v[2*i+1]) << 16) | (unsigned int)f2bf(v[2*i]);
      *(u32x4*)&b_lds[buf ^ 1][c_l * LDB + w8] = d;
    }
    __syncthreads();
  }

  // epilogue: per-row moment partials over this block's 64 cols.
  // C/D layout: col = lane&15, row = (lane>>4)*4 + reg.
  float* mrep = moments_rep + (size_t)(blockIdx.x & (NREP - 1)) * 5 * B_ROWS;
  #pragma unroll
  for (int mi = 0; mi < 4; ++mi) {
    #pragma unroll
    for (int r = 0; r < 4; ++r) {
      const int row = wrow + mi * 16 + g * 4 + r;
      const int lbl = lds_label[row];
      float sa = 0.f, s1 = 0.f, s2 = 0.f, s3 = 0.f, s4 = 0.f;
      #pragma unroll
      for (int ni = 0; ni < 4; ++ni) {
        const float x = acc[mi][ni][r];
        const int col = c0 + ni * 16 + l16;
        if (col == lbl) t_orig[row] = x;   // unique writer across the grid
        const float ax = fabsf(x), x2 = x * x;
        sa += ax; s1 += x; s2 += x2; s3 += x2 * x; s4 += x2 * x2;
      }
      #pragma unroll
      for (int m = 1; m < 16; m <<= 1) {
        sa += __shfl_xor(sa, m);
        s1 += __shfl_xor(s1, m);
        s2 += __shfl_xor(s2, m);
        s3 += __shfl_xor(s3, m);
        s4 += __shfl_xor(s4, m);
      }
      if (l16 == 0) {   // 4 lanes, 4 distinct rows; replica -> ~no contention
        atomicAdd(&mrep[0 * B_ROWS + row], sa);
        atomicAdd(&mrep[1 * B_ROWS + row], s1);
        atomicAdd(&mrep[2 * B_ROWS + row], s2);
        atomicAdd(&mrep[3 * B_ROWS + row], s3);
        atomicAdd(&mrep[4 * B_ROWS + row], s4);
      }
    }
  }
}

// ------- K3: reduce replicas, per-row series LSE + margin + mean (f64) -------
__global__ __launch_bounds__(512)
void loss_kernel(const float* __restrict__ moments_rep,
                 const float* __restrict__ t_orig,
                 float* __restrict__ out) {
  const int r = threadIdx.x;
  double A = 0.0, S1 = 0.0, S2 = 0.0, S3 = 0.0, S4 = 0.0;
  #pragma unroll 4
  for (int b = 0; b < NREP; ++b) {
    const float* m = moments_rep + (size_t)b * 5 * B_ROWS;
    A  += (double)m[0 * B_ROWS + r];
    S1 += (double)m[1 * B_ROWS + r];
    S2 += (double)m[2 * B_ROWS + r];
    S3 += (double)m[3 * B_ROWS + r];
    S4 += (double)m[4 * B_ROWS + r];
  }
  const double to = (double)t_orig[r];
  const double z  = 64.0 / A;   // S / sum|x|
  double sumexp = (double)C_COLS
                + z * (S1 + z * (0.5 * S2 + z * ((1.0/6.0) * S3 + z * (1.0/24.0) * S4)));
  double t = to / A;
  t = fmin(fmax(t, -1.0), 1.0);
  const double tm = cos(acos(t) + 0.5);          // margin M = 0.5
  sumexp += exp(64.0 * tm) - exp(z * to);        // swap target term exactly
  double v = log(sumexp) - 64.0 * tm;            // lse - s*t_m

  #pragma unroll
  for (int m = 1; m < 64; m <<= 1) v += __shfl_xor(v, m);
  __shared__ double red[8];
  if ((r & 63) == 0) red[r >> 6] = v;
  __syncthreads();
  if (r == 0) {
    double tot = 0.0;
    #pragma unroll
    for (int i = 0; i < 8; ++i) tot += red[i];
    out[0] = (float)(tot / (double)B_ROWS);
  }
}

extern "C" void kernel_launch(void* const* d_in, const int* in_sizes, int n_in,
                              void* d_out, int out_size, void* d_ws, size_t ws_size,
                              hipStream_t stream) {
  const float*     feature = (const float*)d_in[0];
  const float*     header  = (const float*)d_in[1];
  const long long* label   = (const long long*)d_in[2];
  float* out = (float*)d_out;

  // ws layout: mrep[64][5][512] f32 | t_orig[512] f32 | feat_bf[512*512] bf16
  float* mrep   = (float*)d_ws;
  float* t_orig = mrep + NREP * 5 * B_ROWS;
  unsigned short* feat_bf = (unsigned short*)(t_orig + B_ROWS);

  hipMemsetAsync(d_ws, 0, (size_t)NREP * 5 * B_ROWS * sizeof(float), stream);
  normalize_kernel<<<B_ROWS, 64, 0, stream>>>(feature, feat_bf);
  const int nblocks = (C_COLS + BN - 1) / BN;   // 1340
  gemm_moments_kernel<<<nblocks, 512, 0, stream>>>(header, feat_bf, label, mrep, t_orig);
  loss_kernel<<<1, 512, 0, stream>>>(mrep, t_orig, out);
}

// Round 7
// 322.792 us; speedup vs baseline: 1.3177x; 1.1208x over previous
//
#include <hip/hip_runtime.h>
#include <math.h>

// ArcFace loss, fully fused, one pass over header:
//   K1: row-normalize feature (f32) -> bf16, written in MFMA-FRAGMENT ORDER
//       P[((wave*16+ks)*4+mi)*64 + lane] so K2's A-loads are fully coalesced
//   K2: bf16-MFMA GEMM over header; per-iter pipeline:
//       [afrag issue][pack hdr(ks+1) -> LDS][issue hdr(ks+2)][bfrag][MFMA]
//       (in-order vmcnt: pack waits vmcnt(4), MFMA waits vmcnt(8) -> hdr(ks+2)
//        always stays in flight across the barrier). Epilogue accumulates
//       per-row moments {S|x|,Sx,Sx^2,Sx^3,Sx^4} + t_orig into 64 replicas.
//   K3: reduce replicas + per-row f64 series LSE + margin + mean
//
// LSE via Taylor moments: |s*x/sum_abs| <= ~0.005 -> 4th-order series is
// ~1e-16 relative. Target-class term swapped exactly in f64.

#define B_ROWS 512
#define K_DIM  512
#define C_COLS 85742
#define BN 64
#define BK 32
#define LDB 40              // bf16 elems per col-row (80B stride, 16B-aligned)
#define NKS (K_DIM / BK)    // 16
#define NREP 64             // moment replica count

typedef float  f32x4  __attribute__((ext_vector_type(4)));
typedef short  bf16x8 __attribute__((ext_vector_type(8)));
typedef unsigned short u16x8 __attribute__((ext_vector_type(8)));
typedef unsigned int   u32x4 __attribute__((ext_vector_type(4)));

__device__ __forceinline__ unsigned short f2bf(float f) {
  unsigned int u = __float_as_uint(f);
  u += 0x7fffu + ((u >> 16) & 1u);
  return (unsigned short)(u >> 16);
}

// ---- K1: L2-normalize rows, emit bf16 in K2's A-fragment order --------------
// K2 reads afrag[mi] at P + (((wave*16+ks)*4+mi)*64 + lane)*8 elems.
// Row row = wave*64 + mi*16 + l16; chunk k = ks*32 + g*8; lane = g*16+l16.
__global__ __launch_bounds__(64)
void normalize_pack_kernel(const float* __restrict__ feature,
                           unsigned short* __restrict__ featP) {
  const int row  = blockIdx.x;
  const int lane = threadIdx.x;
  const float* src = feature + (size_t)row * K_DIM + lane * 8;
  f32x4 v0 = *(const f32x4*)src;
  f32x4 v1 = *(const f32x4*)(src + 4);
  float ss = v0[0]*v0[0] + v0[1]*v0[1] + v0[2]*v0[2] + v0[3]*v0[3]
           + v1[0]*v1[0] + v1[1]*v1[1] + v1[2]*v1[2] + v1[3]*v1[3];
  #pragma unroll
  for (int m = 1; m < 64; m <<= 1) ss += __shfl_xor(ss, m);
  const float scale = 1.0f / fmaxf(sqrtf(ss), 1e-12f);
  u16x8 o;
  o[0] = f2bf(v0[0] * scale); o[1] = f2bf(v0[1] * scale);
  o[2] = f2bf(v0[2] * scale); o[3] = f2bf(v0[3] * scale);
  o[4] = f2bf(v1[0] * scale); o[5] = f2bf(v1[1] * scale);
  o[6] = f2bf(v1[2] * scale); o[7] = f2bf(v1[3] * scale);
  const int w  = row >> 6, mi = (row >> 4) & 3, l16 = row & 15;
  const int ks = lane >> 2, g  = lane & 3;      // this thread's 8-elem k-chunk
  const size_t idx16 = (((size_t)w * 16 + ks) * 4 + mi) * 64 + g * 16 + l16;
  *(u16x8*)(featP + idx16 * 8) = o;
}

// ------- K2: fused GEMM (BM=512 all rows, BN=64 cols/block) + moments --------
__global__ __launch_bounds__(512, 4)   // 4 waves/EU -> 2 blocks/CU
void gemm_moments_kernel(const float* __restrict__ header,
                         const unsigned short* __restrict__ featP,
                         const long long* __restrict__ label,
                         float* __restrict__ moments_rep,  // [NREP][5][512]
                         float* __restrict__ t_orig) {     // [512]
  __shared__ unsigned short b_lds[2][BN * LDB];
  __shared__ int lds_label[B_ROWS];

  const int tid = threadIdx.x;
  const int c0  = blockIdx.x * BN;

  lds_label[tid] = (int)label[tid];   // 512 threads == 512 rows

  const int wave = tid >> 6;
  const int lane = tid & 63;
  const int g    = lane >> 4;
  const int l16  = lane & 15;
  const int wrow = wave * 64;

  // staging: 256 threads; thread = (col c_l in [0,64), k-octet w8 in {0,8,16,24})
  const bool stager = tid < 256;
  const int  c_l    = tid & 63;
  const int  w8     = (tid >> 6) * 8;
  const bool cok    = (c0 + c_l) < C_COLS;
  const int  cg     = cok ? (c0 + c_l) : 0;   // clamp OOB cols, zero at pack

  f32x4 acc[4][4] = {};
  float v[8];

  // prologue: load+pack hdr(0) -> buf0; then load hdr(1) -> v (stays in flight)
  if (stager) {
    float u[8];
    const float* p = header + (size_t)w8 * C_COLS + cg;
    #pragma unroll
    for (int j = 0; j < 8; ++j) u[j] = p[(size_t)j * C_COLS];
    u32x4 d;
    #pragma unroll
    for (int i = 0; i < 4; ++i) {
      const float a = cok ? u[2*i]   : 0.f;
      const float b = cok ? u[2*i+1] : 0.f;
      d[i] = ((unsigned int)f2bf(b) << 16) | (unsigned int)f2bf(a);
    }
    *(u32x4*)&b_lds[0][c_l * LDB + w8] = d;
    const float* p1 = header + ((size_t)BK + w8) * C_COLS + cg;
    #pragma unroll
    for (int j = 0; j < 8; ++j) v[j] = p1[(size_t)j * C_COLS];
  }
  __syncthreads();

  for (int ks = 0; ks < NKS; ++ks) {
    const int buf = ks & 1;

    // 1) afrag issue FIRST (fully coalesced 1KB/wave from packed layout)
    bf16x8 afrag[4];
    #pragma unroll
    for (int mi = 0; mi < 4; ++mi)
      afrag[mi] = *(const bf16x8*)(featP +
                   ((((size_t)wave * 16 + ks) * 4 + mi) * 64 + lane) * 8);
    __builtin_amdgcn_sched_barrier(0);   // pin: afrag issued before v-wait

    // 2) pack v (= hdr ks+1, issued last iter) -> LDS[buf^1].
    //    waits vmcnt(4): afrag stays in flight.
    if (stager && ks + 1 < NKS) {
      u32x4 d;
      #pragma unroll
      for (int i = 0; i < 4; ++i) {
        const float a = cok ? v[2*i]   : 0.f;
        const float b = cok ? v[2*i+1] : 0.f;
        d[i] = ((unsigned int)f2bf(b) << 16) | (unsigned int)f2bf(a);
      }
      *(u32x4*)&b_lds[buf ^ 1][c_l * LDB + w8] = d;
    }

    // 3) issue hdr(ks+2) -> v; newest loads, survive MFMA's vmcnt(8) AND the
    //    barrier -> a full K-step of latency cover.
    if (stager && ks + 2 < NKS) {
      const float* p = header + ((size_t)(ks + 2) * BK + w8) * C_COLS + cg;
      #pragma unroll
      for (int j = 0; j < 8; ++j) v[j] = p[(size_t)j * C_COLS];
    }
    __builtin_amdgcn_sched_barrier(0);   // pin: hdr issued before bfrag/MFMA

    // 4) bfrag LDS reads (2 dwords/bank -> b128 minimum, conflict-free)
    bf16x8 bfrag[4];
    #pragma unroll
    for (int ni = 0; ni < 4; ++ni)
      bfrag[ni] = *(const bf16x8*)&b_lds[buf][(ni * 16 + l16) * LDB + g * 8];

    // 5) MFMAs (wait afrag only: vmcnt(8))
    #pragma unroll
    for (int mi = 0; mi < 4; ++mi)
      #pragma unroll
      for (int ni = 0; ni < 4; ++ni)
        acc[mi][ni] = __builtin_amdgcn_mfma_f32_16x16x32_bf16(
                        afrag[mi], bfrag[ni], acc[mi][ni], 0, 0, 0);

    __syncthreads();
  }

  // epilogue: per-row moment partials over this block's 64 cols.
  // C/D layout: col = lane&15, row = (lane>>4)*4 + reg.
  float* mrep = moments_rep + (size_t)(blockIdx.x & (NREP - 1)) * 5 * B_ROWS;
  #pragma unroll
  for (int mi = 0; mi < 4; ++mi) {
    #pragma unroll
    for (int r = 0; r < 4; ++r) {
      const int row = wrow + mi * 16 + g * 4 + r;
      const int lbl = lds_label[row];
      float sa = 0.f, s1 = 0.f, s2 = 0.f, s3 = 0.f, s4 = 0.f;
      #pragma unroll
      for (int ni = 0; ni < 4; ++ni) {
        const float x = acc[mi][ni][r];
        const int col = c0 + ni * 16 + l16;
        if (col == lbl) t_orig[row] = x;   // unique writer across the grid
        const float ax = fabsf(x), x2 = x * x;
        sa += ax; s1 += x; s2 += x2; s3 += x2 * x; s4 += x2 * x2;
      }
      #pragma unroll
      for (int m = 1; m < 16; m <<= 1) {
        sa += __shfl_xor(sa, m);
        s1 += __shfl_xor(s1, m);
        s2 += __shfl_xor(s2, m);
        s3 += __shfl_xor(s3, m);
        s4 += __shfl_xor(s4, m);
      }
      if (l16 == 0) {   // 4 lanes, 4 distinct rows; replica -> low contention
        atomicAdd(&mrep[0 * B_ROWS + row], sa);
        atomicAdd(&mrep[1 * B_ROWS + row], s1);
        atomicAdd(&mrep[2 * B_ROWS + row], s2);
        atomicAdd(&mrep[3 * B_ROWS + row], s3);
        atomicAdd(&mrep[4 * B_ROWS + row], s4);
      }
    }
  }
}

// ------- K3: reduce replicas, per-row series LSE + margin + mean (f64) -------
__global__ __launch_bounds__(512)
void loss_kernel(const float* __restrict__ moments_rep,
                 const float* __restrict__ t_orig,
                 float* __restrict__ out) {
  const int r = threadIdx.x;
  double A = 0.0, S1 = 0.0, S2 = 0.0, S3 = 0.0, S4 = 0.0;
  #pragma unroll 4
  for (int b = 0; b < NREP; ++b) {
    const float* m = moments_rep + (size_t)b * 5 * B_ROWS;
    A  += (double)m[0 * B_ROWS + r];
    S1 += (double)m[1 * B_ROWS + r];
    S2 += (double)m[2 * B_ROWS + r];
    S3 += (double)m[3 * B_ROWS + r];
    S4 += (double)m[4 * B_ROWS + r];
  }
  const double to = (double)t_orig[r];
  const double z  = 64.0 / A;   // S / sum|x|
  double sumexp = (double)C_COLS
                + z * (S1 + z * (0.5 * S2 + z * ((1.0/6.0) * S3 + z * (1.0/24.0) * S4)));
  double t = to / A;
  t = fmin(fmax(t, -1.0), 1.0);
  const double tm = cos(acos(t) + 0.5);          // margin M = 0.5
  sumexp += exp(64.0 * tm) - exp(z * to);        // swap target term exactly
  double v = log(sumexp) - 64.0 * tm;            // lse - s*t_m

  #pragma unroll
  for (int m = 1; m < 64; m <<= 1) v += __shfl_xor(v, m);
  __shared__ double red[8];
  if ((r & 63) == 0) red[r >> 6] = v;
  __syncthreads();
  if (r == 0) {
    double tot = 0.0;
    #pragma unroll
    for (int i = 0; i < 8; ++i) tot += red[i];
    out[0] = (float)(tot / (double)B_ROWS);
  }
}

extern "C" void kernel_launch(void* const* d_in, const int* in_sizes, int n_in,
                              void* d_out, int out_size, void* d_ws, size_t ws_size,
                              hipStream_t stream) {
  const float*     feature = (const float*)d_in[0];
  const float*     header  = (const float*)d_in[1];
  const long long* label   = (const long long*)d_in[2];
  float* out = (float*)d_out;

  // ws layout: mrep[64][5][512] f32 | t_orig[512] f32 | featP[512*512] bf16
  float* mrep   = (float*)d_ws;
  float* t_orig = mrep + NREP * 5 * B_ROWS;
  unsigned short* featP = (unsigned short*)(t_orig + B_ROWS);

  hipMemsetAsync(d_ws, 0, (size_t)NREP * 5 * B_ROWS * sizeof(float), stream);
  normalize_pack_kernel<<<B_ROWS, 64, 0, stream>>>(feature, featP);
  const int nblocks = (C_COLS + BN - 1) / BN;   // 1340
  gemm_moments_kernel<<<nblocks, 512, 0, stream>>>(header, featP, label, mrep, t_orig);
  loss_kernel<<<1, 512, 0, stream>>>(mrep, t_orig, out);
}